// Round 1
// baseline (97673.199 us; speedup 1.0000x reference)
//
#include <hip/hip_runtime.h>
#include <cstdint>
#include <cstddef>

#define B_ 64
#define T_ 512
#define D_ 300
#define DP_ 320
#define H_ 256
#define G4_ 1024
#define NL_ 6

typedef float f32x4 __attribute__((ext_vector_type(4)));
typedef __bf16 bf16x8 __attribute__((ext_vector_type(8)));

struct WPtrs { const float* W[NL_]; const float* Bv[NL_]; };

__device__ __forceinline__ unsigned short f2bf(float f){
  unsigned int u = __float_as_uint(f);
  unsigned int r = u + 0x7FFFu + ((u >> 16) & 1u);
  return (unsigned short)(r >> 16);
}
__device__ __forceinline__ float bf2f(unsigned int s){
  return __uint_as_float((s & 0xFFFFu) << 16);
}
__device__ __forceinline__ float fast_sig(float x){
  return __builtin_amdgcn_rcpf(1.f + __builtin_amdgcn_exp2f(-1.4426950408889634f * x));
}
__device__ __forceinline__ float fast_tanh(float x){
  return 1.f - 2.f * __builtin_amdgcn_rcpf(1.f + __builtin_amdgcn_exp2f(2.8853900817779268f * x));
}
__device__ __forceinline__ void store8bf(unsigned short* p, const unsigned short v[8]){
  uint4 u;
  u.x = (unsigned)v[0] | ((unsigned)v[1] << 16);
  u.y = (unsigned)v[2] | ((unsigned)v[3] << 16);
  u.z = (unsigned)v[4] | ((unsigned)v[5] << 16);
  u.w = (unsigned)v[6] | ((unsigned)v[7] << 16);
  *(uint4*)p = u;
}

// ---------- Phase 0a: x -> bf16 padded (DP=320), plus reversed copy ----------
__global__ void k_prep_x(const float* __restrict__ x, const int* __restrict__ len,
                         unsigned short* __restrict__ xb, unsigned short* __restrict__ xrb){
  int idx = blockIdx.x * 256 + threadIdx.x;            // over B*T*(DP/8) = 64*512*40
  int d8 = idx % 40;
  int bt = idx / 40;
  if (bt >= B_ * T_) return;
  int t = bt & (T_ - 1);
  int b = bt >> 9;
  int L = len[b];
  int tdst = (t < L) ? (L - 1 - t) : t;                // involution: xrb[b][tdst] = xb[b][t]
  const float* xs = x + (size_t)bt * D_;
  unsigned short v[8];
  #pragma unroll
  for (int e = 0; e < 8; e++){
    int d = d8 * 8 + e;
    v[e] = f2bf(d < D_ ? xs[d] : 0.f);
  }
  store8bf(xb + (size_t)bt * DP_ + d8 * 8, v);
  store8bf(xrb + ((size_t)b * T_ + tdst) * DP_ + d8 * 8, v);
}

// ---------- Phase 0b: prepack weights ----------
// whp[l][ct64][kt8][lane64][e8]  (B-frag layout for 16x16x32 bf16, K=H rows 300..555 of W)
// wxp[l][ct64][kt10][lane64][e8] (K=DP rows 0..299 of W, zero-padded)
// w1t[k16][1024] = W1^T (zero-padded k), w2t likewise
__global__ void k_prep_w(WPtrs wp, unsigned short* __restrict__ whp,
                         unsigned short* __restrict__ wxp,
                         const float* __restrict__ W1, const float* __restrict__ W2,
                         float* __restrict__ w1t, float* __restrict__ w2t){
  int idx = blockIdx.x * 256 + threadIdx.x;
  const int nWh = NL_ * 64 * 8 * 64;      // 196608
  const int nWx = NL_ * 64 * 10 * 64;     // 245760
  if (idx < nWh){
    int lane = idx & 63, kt = (idx >> 6) & 7, ct = (idx >> 9) & 63, l = idx >> 15;
    int col = ct * 16 + (lane & 15);
    int k0 = kt * 32 + (lane >> 4) * 8;
    const float* W = wp.W[l];
    unsigned short v[8];
    #pragma unroll
    for (int e = 0; e < 8; e++) v[e] = f2bf(W[(size_t)(D_ + k0 + e) * G4_ + col]);
    store8bf(whp + ((((size_t)l * 64 + ct) * 8 + kt) * 64 + lane) * 8, v);
  } else if (idx < nWh + nWx){
    int i2 = idx - nWh;
    int lane = i2 & 63;
    int kt = (i2 >> 6) % 10;
    int ct = (i2 / 640) & 63;
    int l = i2 / 40960;
    int col = ct * 16 + (lane & 15);
    int k0 = kt * 32 + (lane >> 4) * 8;
    const float* W = wp.W[l];
    unsigned short v[8];
    #pragma unroll
    for (int e = 0; e < 8; e++){
      int k = k0 + e;
      v[e] = f2bf(k < D_ ? W[(size_t)k * G4_ + col] : 0.f);
    }
    store8bf(wxp + ((((size_t)l * 64 + ct) * 10 + kt) * 64 + lane) * 8, v);
  } else if (idx < nWh + nWx + 16384){
    int i2 = idx - nWh - nWx;
    int h = i2 & 1023, k = i2 >> 10;
    w1t[k * G4_ + h] = (k < 10) ? W1[h * 10 + k] : 0.f;
  } else if (idx < nWh + nWx + 32768){
    int i2 = idx - nWh - nWx - 16384;
    int h = i2 & 1023, k = i2 >> 10;
    w2t[k * G4_ + h] = (k < 12) ? W2[h * 12 + k] : 0.f;
  }
}

// ---------- Phase 1: P[li][t][ct][mt][lane][4] = (x or xrev) @ Wx + b  (bf16, frag layout) ----------
__global__ __launch_bounds__(256, 2) void k_pgemm(
    const unsigned short* __restrict__ xb, const unsigned short* __restrict__ xrb,
    const unsigned short* __restrict__ wxp, WPtrs wp,
    unsigned short* __restrict__ P, int l0, int nl){
  int bx = blockIdx.x;
  int li = bx >> 10;
  int rem = bx & 1023;
  int t = rem & 511;
  int nh = rem >> 9;
  int lg = l0 + li;
  const unsigned short* A = (lg & 1) ? xrb : xb;
  __shared__ unsigned short Alds[64 * 40];   // rows padded to 80B (2-way max bank alias)
  int tid = threadIdx.x;
  int lane = tid & 63;
  int w = tid >> 6;
  f32x4 acc[4][8];
  #pragma unroll
  for (int mt = 0; mt < 4; mt++)
    #pragma unroll
    for (int nt = 0; nt < 8; nt++){
      acc[mt][nt].x = 0.f; acc[mt][nt].y = 0.f; acc[mt][nt].z = 0.f; acc[mt][nt].w = 0.f;
    }
  int row = tid >> 2, q = tid & 3;
  const unsigned short* asrc = A + ((size_t)row * T_ + t) * DP_ + q * 8;
  for (int kt = 0; kt < 10; kt++){
    __syncthreads();
    *(uint4*)(&Alds[row * 40 + q * 8]) = *(const uint4*)(asrc + kt * 32);
    __syncthreads();
    bf16x8 Af[4];
    #pragma unroll
    for (int mt = 0; mt < 4; mt++)
      Af[mt] = *(const bf16x8*)(&Alds[(mt * 16 + (lane & 15)) * 40 + (lane >> 4) * 8]);
    #pragma unroll
    for (int nt = 0; nt < 8; nt++){
      int ct = nh * 32 + w * 8 + nt;
      bf16x8 Bf = *(const bf16x8*)(wxp + ((((size_t)lg * 64 + ct) * 10 + kt) * 64 + lane) * 8);
      #pragma unroll
      for (int mt = 0; mt < 4; mt++)
        acc[mt][nt] = __builtin_amdgcn_mfma_f32_16x16x32_bf16(Af[mt], Bf, acc[mt][nt], 0, 0, 0);
    }
  }
  #pragma unroll
  for (int nt = 0; nt < 8; nt++){
    int ct = nh * 32 + w * 8 + nt;
    int col = ct * 16 + (lane & 15);
    float bias = wp.Bv[lg][col];
    #pragma unroll
    for (int mt = 0; mt < 4; mt++){
      uint2 uo;
      uo.x = (unsigned)f2bf(acc[mt][nt].x + bias) | ((unsigned)f2bf(acc[mt][nt].y + bias) << 16);
      uo.y = (unsigned)f2bf(acc[mt][nt].z + bias) | ((unsigned)f2bf(acc[mt][nt].w + bias) << 16);
      *(uint2*)(P + (((((size_t)li * T_ + t) * 64 + ct) * 4 + mt) * 64 + lane) * 4) = uo;
    }
  }
}

// ---------- Phase 2: recurrent LSTM (B-frags register-resident, flag-sync across 16 wgs/LSTM) ----------
__global__ __launch_bounds__(256, 1) void k_rec(
    const unsigned short* __restrict__ whp, const unsigned short* __restrict__ P,
    const int* __restrict__ len, unsigned short* __restrict__ hbuf,
    int* __restrict__ cnt, unsigned short* __restrict__ ho, int l0, int nl){
  int l = blockIdx.x & 7;
  if (l >= nl) return;
  int s = blockIdx.x >> 3;            // 0..15 : hidden slice
  int lg = l0 + l;
  int tid = threadIdx.x, lane = tid & 63, w = tid >> 6;
  // register-resident Wh fragments: [gate][kt]
  bf16x8 Bf[4][8];
  #pragma unroll
  for (int g = 0; g < 4; g++){
    int ct = g * 16 + s;
    #pragma unroll
    for (int kt = 0; kt < 8; kt++)
      Bf[g][kt] = *(const bf16x8*)(whp + ((((size_t)lg * 64 + ct) * 8 + kt) * 64 + lane) * 8);
  }
  float c4[4] = {0.f, 0.f, 0.f, 0.f};
  float h4[4] = {0.f, 0.f, 0.f, 0.f};
  int Lr[4];
  #pragma unroll
  for (int r = 0; r < 4; r++) Lr[r] = len[w * 16 + (lane >> 4) * 4 + r];
  int hid = s * 16 + (lane & 15);
  unsigned short* hb0 = hbuf + (size_t)(0 * NL_ + l) * B_ * H_;
  unsigned short* hb1 = hbuf + (size_t)(1 * NL_ + l) * B_ * H_;
  int* mycnt = cnt + l * T_;
  int arow = w * 16 + (lane & 15);
  const int isbw = lg & 1;
  for (int t = 0; t < T_; t++){
    if (t > 0){
      if (lane == 0){
        int guard = 0;
        while (__hip_atomic_load(&mycnt[t - 1], __ATOMIC_ACQUIRE, __HIP_MEMORY_SCOPE_AGENT) < 16){
          if (++guard > (1 << 22)) break;   // safety: never hang the GPU
          __builtin_amdgcn_s_sleep(1);
        }
      }
      __threadfence();
    }
    const unsigned short* hsrc = ((t & 1) ? hb0 : hb1) + (size_t)arow * H_ + (lane >> 4) * 8;
    bf16x8 Af[8];
    #pragma unroll
    for (int kt = 0; kt < 8; kt++)
      Af[kt] = *(const bf16x8*)(hsrc + kt * 32);
    f32x4 acc[4];
    #pragma unroll
    for (int g = 0; g < 4; g++){
      int ct = g * 16 + s;
      uint2 pv = *(const uint2*)(P + (((((size_t)l * T_ + t) * 64 + ct) * 4 + w) * 64 + lane) * 4);
      acc[g].x = bf2f(pv.x); acc[g].y = bf2f(pv.x >> 16);
      acc[g].z = bf2f(pv.y); acc[g].w = bf2f(pv.y >> 16);
    }
    #pragma unroll
    for (int kt = 0; kt < 8; kt++)
      #pragma unroll
      for (int g = 0; g < 4; g++)
        acc[g] = __builtin_amdgcn_mfma_f32_16x16x32_bf16(Af[kt], Bf[g][kt], acc[g], 0, 0, 0);
    unsigned short* hdst = (t & 1) ? hb1 : hb0;
    #pragma unroll
    for (int r = 0; r < 4; r++){
      float gi = acc[0][r], gj = acc[1][r], gf = acc[2][r], go = acc[3][r];
      float cn = fast_sig(gf + 1.f) * c4[r] + fast_sig(gi) * fast_tanh(gj);
      float hn = fast_sig(go) * fast_tanh(cn);
      bool m = (t < Lr[r]);
      c4[r] = m ? cn : c4[r];
      h4[r] = m ? hn : h4[r];
      int b = w * 16 + (lane >> 4) * 4 + r;
      int tdst = isbw ? ((t < Lr[r]) ? (Lr[r] - 1 - t) : t) : t;
      ho[(((size_t)b * T_ + tdst) * NL_ + lg) * H_ + hid] = f2bf(m ? hn : 0.f);
      hdst[(size_t)b * H_ + hid] = f2bf(h4[r]);
    }
    __threadfence();
    __syncthreads();
    if (tid == 0)
      __hip_atomic_fetch_add(&mycnt[t], 1, __ATOMIC_RELEASE, __HIP_MEMORY_SCOPE_AGENT);
  }
}

// ---------- Phase 3: logits = concat(ho) @ W + b  (wave per (b,t)) ----------
__global__ void k_logits(const unsigned short* __restrict__ ho,
                         const float* __restrict__ w1t, const float* __restrict__ w2t,
                         const float* __restrict__ b1, const float* __restrict__ b2,
                         float* __restrict__ lgt){
  int gid = blockIdx.x * 4 + (threadIdx.x >> 6);   // 0..32767 = b*512+t
  int lane = threadIdx.x & 63;
  const unsigned short* hrow = ho + (size_t)gid * (NL_ * H_);
  float hv[6][4];
  #pragma unroll
  for (int lgi = 0; lgi < 6; lgi++){
    uint2 u = *(const uint2*)(hrow + lgi * H_ + lane * 4);
    hv[lgi][0] = bf2f(u.x); hv[lgi][1] = bf2f(u.x >> 16);
    hv[lgi][2] = bf2f(u.y); hv[lgi][3] = bf2f(u.y >> 16);
  }
  float s1[10], s2[12];
  #pragma unroll
  for (int k = 0; k < 10; k++) s1[k] = 0.f;
  #pragma unroll
  for (int k = 0; k < 12; k++) s2[k] = 0.f;
  const int seg1[4] = {0, 1, 4, 5};
  const int seg2[4] = {2, 3, 4, 5};
  #pragma unroll
  for (int k = 0; k < 10; k++){
    #pragma unroll
    for (int ii = 0; ii < 4; ii++){
      float4 wv = *(const float4*)(w1t + k * G4_ + ii * 256 + lane * 4);
      int lgi = seg1[ii];
      s1[k] += hv[lgi][0] * wv.x + hv[lgi][1] * wv.y + hv[lgi][2] * wv.z + hv[lgi][3] * wv.w;
    }
  }
  #pragma unroll
  for (int k = 0; k < 12; k++){
    #pragma unroll
    for (int ii = 0; ii < 4; ii++){
      float4 wv = *(const float4*)(w2t + k * G4_ + ii * 256 + lane * 4);
      int lgi = seg2[ii];
      s2[k] += hv[lgi][0] * wv.x + hv[lgi][1] * wv.y + hv[lgi][2] * wv.z + hv[lgi][3] * wv.w;
    }
  }
  #pragma unroll
  for (int k = 0; k < 10; k++)
    #pragma unroll
    for (int d = 1; d < 64; d <<= 1) s1[k] += __shfl_xor(s1[k], d, 64);
  #pragma unroll
  for (int k = 0; k < 12; k++)
    #pragma unroll
    for (int d = 1; d < 64; d <<= 1) s2[k] += __shfl_xor(s2[k], d, 64);
  if (lane == 0){
    int b = gid >> 9, t = gid & 511;
    float* o1 = lgt + ((size_t)(0 * B_ + b) * T_ + t) * 16;
    float* o2 = lgt + ((size_t)(1 * B_ + b) * T_ + t) * 16;
    #pragma unroll
    for (int k = 0; k < 10; k++) o1[k] = s1[k] + b1[k];
    #pragma unroll
    for (int k = 0; k < 12; k++) o2[k] = s2[k] + b2[k];
  }
}

// ---------- Phase 4: CRF NLL (wave per (task, b)) ----------
__global__ void k_crf(const float* __restrict__ lgt, const int* __restrict__ labels,
                      const int* __restrict__ len, const float* __restrict__ trans1,
                      const float* __restrict__ trans2, float* __restrict__ out){
  int gid = blockIdx.x * 4 + (threadIdx.x >> 6);    // 0..127
  int lane = threadIdx.x & 63;
  int tau = gid >> 6;
  int b = gid & 63;
  int K = tau ? 12 : 10;
  const float* tr = tau ? trans2 : trans1;
  const float* lgp = lgt + (size_t)(tau * B_ + b) * T_ * 16;
  int L = len[b];
  int k2 = lane & 15;
  const float LOG2E = 1.4426950408889634f;
  const float LN2 = 0.6931471805599453f;
  float Et[12];
  #pragma unroll
  for (int k1 = 0; k1 < 12; k1++)
    Et[k1] = (k1 < K && k2 < K) ? __builtin_amdgcn_exp2f(LOG2E * tr[k1 * K + k2]) : 0.f;
  float alpha = (k2 < K) ? lgp[k2] : -1e30f;
  for (int t = 1; t < L; t++){
    float m = alpha;
    #pragma unroll
    for (int d = 1; d < 16; d <<= 1) m = fmaxf(m, __shfl_xor(m, d, 16));
    float e = __builtin_amdgcn_exp2f(LOG2E * (alpha - m));
    float ss = 0.f;
    #pragma unroll
    for (int k1 = 0; k1 < 12; k1++)
      ss += __shfl(e, k1, 16) * Et[k1];   // lanes >= K contribute e=0 / Et=0
    float na = m + LN2 * __builtin_amdgcn_logf(ss) + lgp[t * 16 + k2];
    alpha = (k2 < K) ? na : -1e30f;
  }
  float m2 = alpha;
  #pragma unroll
  for (int d = 1; d < 16; d <<= 1) m2 = fmaxf(m2, __shfl_xor(m2, d, 16));
  float e2 = __builtin_amdgcn_exp2f(LOG2E * (alpha - m2));
  #pragma unroll
  for (int d = 1; d < 16; d <<= 1) e2 += __shfl_xor(e2, d, 16);
  float logZ = m2 + LN2 * __builtin_amdgcn_logf(e2);
  float us = 0.f;
  const int* lab = labels + b * T_;
  for (int t0 = lane; t0 < L; t0 += 64){
    int la = lab[t0];
    us += lgp[t0 * 16 + la];
    if (t0 >= 1) us += tr[lab[t0 - 1] * K + la];
  }
  #pragma unroll
  for (int d = 1; d < 64; d <<= 1) us += __shfl_xor(us, d, 64);
  if (lane == 0) out[tau * B_ + b] = logZ - us;
}

extern "C" void kernel_launch(void* const* d_in, const int* in_sizes, int n_in,
                              void* d_out, int out_size, void* d_ws, size_t ws_size,
                              hipStream_t stream){
  const float* x = (const float*)d_in[0];
  const int* len = (const int*)d_in[1];
  const int* labels = (const int*)d_in[2];
  WPtrs wp;
  for (int l = 0; l < NL_; l++){
    wp.W[l] = (const float*)d_in[3 + 2 * l];
    wp.Bv[l] = (const float*)d_in[4 + 2 * l];
  }
  const float* W1 = (const float*)d_in[15];
  const float* b1 = (const float*)d_in[16];
  const float* W2 = (const float*)d_in[17];
  const float* b2 = (const float*)d_in[18];
  const float* trans1 = (const float*)d_in[19];
  const float* trans2 = (const float*)d_in[20];

  char* ws = (char*)d_ws;
  const size_t SZ_SYNC = 2ull * NL_ * B_ * H_ * 2 + (size_t)NL_ * T_ * 4;  // hbuf + cnt = 405504
  const size_t O_XB  = 405504;
  const size_t SZ_X  = (size_t)B_ * T_ * DP_ * 2;                          // 20971520
  const size_t O_XRB = O_XB + SZ_X;
  const size_t O_WHP = O_XRB + SZ_X;
  const size_t SZ_WHP = (size_t)NL_ * H_ * G4_ * 2;                        // 3145728
  const size_t O_WXP = O_WHP + SZ_WHP;
  const size_t SZ_WXP = (size_t)NL_ * DP_ * G4_ * 2;                       // 3932160
  const size_t O_W1T = O_WXP + SZ_WXP;
  const size_t O_W2T = O_W1T + 65536;
  const size_t O_HO  = O_W2T + 65536;
  const size_t SZ_HO = (size_t)B_ * T_ * NL_ * H_ * 2;                     // 100663296
  const size_t O_LGT = O_HO + SZ_HO;
  const size_t SZ_LGT = 2ull * B_ * T_ * 16 * 4;                           // 8388608
  const size_t O_P   = O_LGT + SZ_LGT;
  const size_t SZ_P1 = (size_t)T_ * 64 * 4 * 64 * 4 * 2;                   // 67108864 per LSTM

  unsigned short* hbuf = (unsigned short*)(ws + 0);
  int* cnt = (int*)(ws + 2ull * NL_ * B_ * H_ * 2);
  unsigned short* xb  = (unsigned short*)(ws + O_XB);
  unsigned short* xrb = (unsigned short*)(ws + O_XRB);
  unsigned short* whp = (unsigned short*)(ws + O_WHP);
  unsigned short* wxp = (unsigned short*)(ws + O_WXP);
  float* w1t = (float*)(ws + O_W1T);
  float* w2t = (float*)(ws + O_W2T);
  unsigned short* ho = (unsigned short*)(ws + O_HO);
  float* lgt = (float*)(ws + O_LGT);
  unsigned short* P = (unsigned short*)(ws + O_P);

  int glen = 6;
  if (ws_size < O_P + 6 * SZ_P1) glen = (ws_size >= O_P + 2 * SZ_P1) ? 2 : 1;

  k_prep_x<<<5120, 256, 0, stream>>>(x, len, xb, xrb);
  k_prep_w<<<1856, 256, 0, stream>>>(wp, whp, wxp, W1, W2, w1t, w2t);
  for (int l0 = 0; l0 < NL_; l0 += glen){
    int nl = glen;
    k_pgemm<<<nl * 1024, 256, 0, stream>>>(xb, xrb, wxp, wp, P, l0, nl);
    hipMemsetAsync(ws, 0, SZ_SYNC, stream);
    k_rec<<<128, 256, 0, stream>>>(whp, P, len, hbuf, cnt, ho, l0, nl);
  }
  k_logits<<<8192, 256, 0, stream>>>(ho, w1t, w2t, b1, b2, lgt);
  k_crf<<<32, 256, 0, stream>>>(lgt, labels, len, trans1, trans2, (float*)d_out);
}

// Round 2
// 3127.828 us; speedup vs baseline: 31.2272x; 31.2272x over previous
//
#include <hip/hip_runtime.h>
#include <cstdint>
#include <cstddef>

#define B_ 64
#define T_ 512
#define D_ 300
#define DP_ 320
#define H_ 256
#define G4_ 1024
#define NL_ 6

typedef float f32x4 __attribute__((ext_vector_type(4)));
typedef __bf16 bf16x8 __attribute__((ext_vector_type(8)));

struct WPtrs { const float* W[NL_]; const float* Bv[NL_]; };

__device__ __forceinline__ unsigned short f2bf(float f){
  unsigned int u = __float_as_uint(f);
  unsigned int r = u + 0x7FFFu + ((u >> 16) & 1u);
  return (unsigned short)(r >> 16);
}
__device__ __forceinline__ float bf2f(unsigned int s){
  return __uint_as_float((s & 0xFFFFu) << 16);
}
__device__ __forceinline__ float fast_sig(float x){
  return __builtin_amdgcn_rcpf(1.f + __builtin_amdgcn_exp2f(-1.4426950408889634f * x));
}
__device__ __forceinline__ float fast_tanh(float x){
  return 1.f - 2.f * __builtin_amdgcn_rcpf(1.f + __builtin_amdgcn_exp2f(2.8853900817779268f * x));
}
__device__ __forceinline__ void store8bf(unsigned short* p, const unsigned short v[8]){
  uint4 u;
  u.x = (unsigned)v[0] | ((unsigned)v[1] << 16);
  u.y = (unsigned)v[2] | ((unsigned)v[3] << 16);
  u.z = (unsigned)v[4] | ((unsigned)v[5] << 16);
  u.w = (unsigned)v[6] | ((unsigned)v[7] << 16);
  *(uint4*)p = u;
}

// ---------- Phase 0a: x -> bf16 padded (DP=320), plus reversed copy ----------
__global__ void k_prep_x(const float* __restrict__ x, const int* __restrict__ len,
                         unsigned short* __restrict__ xb, unsigned short* __restrict__ xrb){
  int idx = blockIdx.x * 256 + threadIdx.x;            // over B*T*(DP/8) = 64*512*40
  int d8 = idx % 40;
  int bt = idx / 40;
  if (bt >= B_ * T_) return;
  int t = bt & (T_ - 1);
  int b = bt >> 9;
  int L = len[b];
  int tdst = (t < L) ? (L - 1 - t) : t;                // involution: xrb[b][tdst] = xb[b][t]
  const float* xs = x + (size_t)bt * D_;
  unsigned short v[8];
  #pragma unroll
  for (int e = 0; e < 8; e++){
    int d = d8 * 8 + e;
    v[e] = f2bf(d < D_ ? xs[d] : 0.f);
  }
  store8bf(xb + (size_t)bt * DP_ + d8 * 8, v);
  store8bf(xrb + ((size_t)b * T_ + tdst) * DP_ + d8 * 8, v);
}

// ---------- Phase 0b: prepack weights ----------
// whp[l][s][g][kt8][lane64][e8]  : Wh B-frags (rows D..D+255 of W), col = g*256+s*16+(lane&15)
// wxp[l][s][kt10][g][lane64][e8] : Wx B-frags (rows 0..299, zero-pad to 320)
// w1t[k16][1024] = W1^T (zero-padded k), w2t likewise
__global__ void k_prep_w(WPtrs wp, unsigned short* __restrict__ whp,
                         unsigned short* __restrict__ wxp,
                         const float* __restrict__ W1, const float* __restrict__ W2,
                         float* __restrict__ w1t, float* __restrict__ w2t){
  int idx = blockIdx.x * 256 + threadIdx.x;
  const int nWh = NL_ * 16 * 4 * 8 * 64;   // 196608
  const int nWx = NL_ * 16 * 10 * 4 * 64;  // 245760
  if (idx < nWh){
    int lane = idx & 63, kt = (idx >> 6) & 7, g = (idx >> 9) & 3, s = (idx >> 11) & 15, l = idx >> 15;
    int col = g * 256 + s * 16 + (lane & 15);
    int k0 = kt * 32 + (lane >> 4) * 8;
    const float* W = wp.W[l];
    unsigned short v[8];
    #pragma unroll
    for (int e = 0; e < 8; e++) v[e] = f2bf(W[(size_t)(D_ + k0 + e) * G4_ + col]);
    store8bf(whp + ((((size_t)(l * 16 + s) * 4 + g) * 8 + kt) * 64 + lane) * 8, v);
  } else if (idx < nWh + nWx){
    int i2 = idx - nWh;
    int lane = i2 & 63;
    int g = (i2 >> 6) & 3;
    int r = i2 >> 8;
    int kt = r % 10;
    int r2 = r / 10;
    int s = r2 & 15, l = r2 >> 4;
    int col = g * 256 + s * 16 + (lane & 15);
    int k0 = kt * 32 + (lane >> 4) * 8;
    const float* W = wp.W[l];
    unsigned short v[8];
    #pragma unroll
    for (int e = 0; e < 8; e++){
      int k = k0 + e;
      v[e] = f2bf(k < D_ ? W[(size_t)k * G4_ + col] : 0.f);
    }
    store8bf(wxp + ((((size_t)(l * 16 + s) * 10 + kt) * 4 + g) * 64 + lane) * 8, v);
  } else if (idx < nWh + nWx + 16384){
    int i2 = idx - nWh - nWx;
    int h = i2 & 1023, k = i2 >> 10;
    w1t[k * G4_ + h] = (k < 10) ? W1[h * 10 + k] : 0.f;
  } else if (idx < nWh + nWx + 32768){
    int i2 = idx - nWh - nWx - 16384;
    int h = i2 & 1023, k = i2 >> 10;
    w2t[k * G4_ + h] = (k < 12) ? W2[h * 12 + k] : 0.f;
  }
}

// ---------- Phase 1: fused recurrent LSTM, all 6 LSTMs concurrent ----------
// 16 wgs per LSTM (one h-slice of 16 cols each), 256 threads (4 waves = 4 batch quarters).
// Wh register-resident; Wx streamed from L2; x@Wx computed per step (no P buffer).
// Sync: fence-free. h published via RELAXED agent atomics (cache-bypass, no wbl2),
// inline-asm vmcnt(0) + barrier, RELAXED atomic flag add; consumers speculative-load h.
__global__ __launch_bounds__(256, 1) void k_rec(
    const unsigned short* __restrict__ whp, const unsigned short* __restrict__ wxp,
    const unsigned short* __restrict__ xb, const unsigned short* __restrict__ xrb,
    WPtrs wp, const int* __restrict__ len,
    unsigned short* __restrict__ hbuf, int* __restrict__ cnt,
    unsigned short* __restrict__ ho){
  int l = blockIdx.x & 7;
  if (l >= NL_) return;
  int s = blockIdx.x >> 3;            // 0..15 : hidden slice
  int tid = threadIdx.x, lane = tid & 63, w = tid >> 6;
  const int isbw = l & 1;
  const unsigned short* xsrc = isbw ? xrb : xb;

  // register-resident Wh fragments Bh[gate][kt]
  bf16x8 Bh[4][8];
  #pragma unroll
  for (int g = 0; g < 4; g++)
    #pragma unroll
    for (int kt = 0; kt < 8; kt++)
      Bh[g][kt] = *(const bf16x8*)(whp + ((((size_t)(l * 16 + s) * 4 + g) * 8 + kt) * 64 + lane) * 8);

  float bias[4];
  #pragma unroll
  for (int g = 0; g < 4; g++) bias[g] = wp.Bv[l][g * 256 + s * 16 + (lane & 15)];

  float c4[4] = {0.f, 0.f, 0.f, 0.f};
  float h4[4] = {0.f, 0.f, 0.f, 0.f};
  int Lr[4];
  #pragma unroll
  for (int r = 0; r < 4; r++) Lr[r] = len[w * 16 + (lane >> 4) * 4 + r];

  int hcol = s * 16 + (lane & 15);
  int arow = w * 16 + (lane & 15);
  int* flag = cnt + l * T_;
  const unsigned short* xrow = xsrc + (size_t)arow * T_ * DP_ + (lane >> 4) * 8;
  const unsigned short* wxs = wxp + (size_t)(l * 16 + s) * 10 * 4 * 64 * 8 + (size_t)lane * 8;
  // h buffers: hbuf[par][l][b][256]; h_t lives in par = t&1
  unsigned short* hb[2];
  hb[0] = hbuf + ((size_t)(0 * NL_ + l) * B_) * H_;
  hb[1] = hbuf + ((size_t)(1 * NL_ + l) * B_) * H_;

  union U16x8 { unsigned long long q[2]; bf16x8 v; };

  for (int t = 0; t < T_; t++){
    // ---- x-phase: acc = x_t @ Wx (independent of h, overlaps others' publish) ----
    f32x4 acc[4];
    #pragma unroll
    for (int g = 0; g < 4; g++){ acc[g].x = 0.f; acc[g].y = 0.f; acc[g].z = 0.f; acc[g].w = 0.f; }
    const unsigned short* xt = xrow + (size_t)t * DP_;
    #pragma unroll
    for (int kt = 0; kt < 10; kt++){
      bf16x8 Ax = *(const bf16x8*)(xt + kt * 32);
      #pragma unroll
      for (int g = 0; g < 4; g++){
        bf16x8 Bx = *(const bf16x8*)(wxs + ((size_t)(kt * 4 + g) * 64) * 8);
        acc[g] = __builtin_amdgcn_mfma_f32_16x16x32_bf16(Ax, Bx, acc[g], 0, 0, 0);
      }
    }
    // ---- h-phase: speculative load of h_{t-1}, verify flag, reload if early ----
    const unsigned short* hrow = hb[(t + 1) & 1] + (size_t)arow * H_ + (lane >> 4) * 8;
    bf16x8 Ah[8];
    #pragma unroll
    for (int kt = 0; kt < 8; kt++){
      U16x8 u;
      u.q[0] = __hip_atomic_load((const unsigned long long*)(hrow + kt * 32), __ATOMIC_RELAXED, __HIP_MEMORY_SCOPE_AGENT);
      u.q[1] = __hip_atomic_load((const unsigned long long*)(hrow + kt * 32) + 1, __ATOMIC_RELAXED, __HIP_MEMORY_SCOPE_AGENT);
      Ah[kt] = u.v;
    }
    if (t > 0){
      int f = __hip_atomic_load(&flag[t - 1], __ATOMIC_RELAXED, __HIP_MEMORY_SCOPE_AGENT);
      if (f < 16){                       // wave-uniform branch
        if (lane == 0){
          int gd = 0;
          while (__hip_atomic_load(&flag[t - 1], __ATOMIC_RELAXED, __HIP_MEMORY_SCOPE_AGENT) < 16){
            __builtin_amdgcn_s_sleep(1);
            if (++gd > (1 << 15)) break;  // safety: never hang
          }
        }
        #pragma unroll
        for (int kt = 0; kt < 8; kt++){
          U16x8 u;
          u.q[0] = __hip_atomic_load((const unsigned long long*)(hrow + kt * 32), __ATOMIC_RELAXED, __HIP_MEMORY_SCOPE_AGENT);
          u.q[1] = __hip_atomic_load((const unsigned long long*)(hrow + kt * 32) + 1, __ATOMIC_RELAXED, __HIP_MEMORY_SCOPE_AGENT);
          Ah[kt] = u.v;
        }
      }
    }
    #pragma unroll
    for (int kt = 0; kt < 8; kt++)
      #pragma unroll
      for (int g = 0; g < 4; g++)
        acc[g] = __builtin_amdgcn_mfma_f32_16x16x32_bf16(Ah[kt], Bh[g][kt], acc[g], 0, 0, 0);

    // ---- gates ----
    unsigned short hpub[4], hov[4];
    #pragma unroll
    for (int r = 0; r < 4; r++){
      float gi = acc[0][r] + bias[0], gj = acc[1][r] + bias[1];
      float gf = acc[2][r] + bias[2], go = acc[3][r] + bias[3];
      float cn = fast_sig(gf + 1.f) * c4[r] + fast_sig(gi) * fast_tanh(gj);
      float hn = fast_sig(go) * fast_tanh(cn);
      bool m = (t < Lr[r]);
      c4[r] = m ? cn : c4[r];
      h4[r] = m ? hn : h4[r];
      hpub[r] = f2bf(h4[r]);
      hov[r] = f2bf(m ? hn : 0.f);
    }
    // ---- publish h_t (cache-bypass stores, no fences) ----
    unsigned short* hdst = hb[t & 1] + hcol;
    #pragma unroll
    for (int r = 0; r < 4; r++){
      int b = w * 16 + (lane >> 4) * 4 + r;
      __hip_atomic_store(hdst + (size_t)b * H_, hpub[r], __ATOMIC_RELAXED, __HIP_MEMORY_SCOPE_AGENT);
    }
    asm volatile("s_waitcnt vmcnt(0)" ::: "memory");
    __syncthreads();
    if (tid == 0)
      __hip_atomic_fetch_add(&flag[t], 1, __ATOMIC_RELAXED, __HIP_MEMORY_SCOPE_AGENT);
    // ---- ho writes (off the critical path) ----
    #pragma unroll
    for (int r = 0; r < 4; r++){
      int b = w * 16 + (lane >> 4) * 4 + r;
      int tdst = isbw ? ((t < Lr[r]) ? (Lr[r] - 1 - t) : t) : t;
      ho[(((size_t)b * T_ + tdst) * NL_ + l) * H_ + hcol] = hov[r];
    }
  }
}

// ---------- Phase 3: logits = concat(ho) @ W + b  (wave per (b,t)) ----------
__global__ void k_logits(const unsigned short* __restrict__ ho,
                         const float* __restrict__ w1t, const float* __restrict__ w2t,
                         const float* __restrict__ b1, const float* __restrict__ b2,
                         float* __restrict__ lgt){
  int gid = blockIdx.x * 4 + (threadIdx.x >> 6);   // 0..32767 = b*512+t
  int lane = threadIdx.x & 63;
  const unsigned short* hrow = ho + (size_t)gid * (NL_ * H_);
  float hv[6][4];
  #pragma unroll
  for (int lgi = 0; lgi < 6; lgi++){
    uint2 u = *(const uint2*)(hrow + lgi * H_ + lane * 4);
    hv[lgi][0] = bf2f(u.x); hv[lgi][1] = bf2f(u.x >> 16);
    hv[lgi][2] = bf2f(u.y); hv[lgi][3] = bf2f(u.y >> 16);
  }
  float s1[10], s2[12];
  #pragma unroll
  for (int k = 0; k < 10; k++) s1[k] = 0.f;
  #pragma unroll
  for (int k = 0; k < 12; k++) s2[k] = 0.f;
  const int seg1[4] = {0, 1, 4, 5};
  const int seg2[4] = {2, 3, 4, 5};
  #pragma unroll
  for (int k = 0; k < 10; k++){
    #pragma unroll
    for (int ii = 0; ii < 4; ii++){
      float4 wv = *(const float4*)(w1t + k * G4_ + ii * 256 + lane * 4);
      int lgi = seg1[ii];
      s1[k] += hv[lgi][0] * wv.x + hv[lgi][1] * wv.y + hv[lgi][2] * wv.z + hv[lgi][3] * wv.w;
    }
  }
  #pragma unroll
  for (int k = 0; k < 12; k++){
    #pragma unroll
    for (int ii = 0; ii < 4; ii++){
      float4 wv = *(const float4*)(w2t + k * G4_ + ii * 256 + lane * 4);
      int lgi = seg2[ii];
      s2[k] += hv[lgi][0] * wv.x + hv[lgi][1] * wv.y + hv[lgi][2] * wv.z + hv[lgi][3] * wv.w;
    }
  }
  #pragma unroll
  for (int k = 0; k < 10; k++)
    #pragma unroll
    for (int d = 1; d < 64; d <<= 1) s1[k] += __shfl_xor(s1[k], d, 64);
  #pragma unroll
  for (int k = 0; k < 12; k++)
    #pragma unroll
    for (int d = 1; d < 64; d <<= 1) s2[k] += __shfl_xor(s2[k], d, 64);
  if (lane == 0){
    int b = gid >> 9, t = gid & 511;
    float* o1 = lgt + ((size_t)(0 * B_ + b) * T_ + t) * 16;
    float* o2 = lgt + ((size_t)(1 * B_ + b) * T_ + t) * 16;
    #pragma unroll
    for (int k = 0; k < 10; k++) o1[k] = s1[k] + b1[k];
    #pragma unroll
    for (int k = 0; k < 12; k++) o2[k] = s2[k] + b2[k];
  }
}

// ---------- Phase 4: CRF NLL (wave per (task, b)) ----------
__global__ void k_crf(const float* __restrict__ lgt, const int* __restrict__ labels,
                      const int* __restrict__ len, const float* __restrict__ trans1,
                      const float* __restrict__ trans2, float* __restrict__ out){
  int gid = blockIdx.x * 4 + (threadIdx.x >> 6);    // 0..127
  int lane = threadIdx.x & 63;
  int tau = gid >> 6;
  int b = gid & 63;
  int K = tau ? 12 : 10;
  const float* tr = tau ? trans2 : trans1;
  const float* lgp = lgt + (size_t)(tau * B_ + b) * T_ * 16;
  int L = len[b];
  int k2 = lane & 15;
  const float LOG2E = 1.4426950408889634f;
  const float LN2 = 0.6931471805599453f;
  float Et[12];
  #pragma unroll
  for (int k1 = 0; k1 < 12; k1++)
    Et[k1] = (k1 < K && k2 < K) ? __builtin_amdgcn_exp2f(LOG2E * tr[k1 * K + k2]) : 0.f;
  float alpha = (k2 < K) ? lgp[k2] : -1e30f;
  for (int t = 1; t < L; t++){
    float m = alpha;
    #pragma unroll
    for (int d = 1; d < 16; d <<= 1) m = fmaxf(m, __shfl_xor(m, d, 16));
    float e = __builtin_amdgcn_exp2f(LOG2E * (alpha - m));
    float ss = 0.f;
    #pragma unroll
    for (int k1 = 0; k1 < 12; k1++)
      ss += __shfl(e, k1, 16) * Et[k1];   // lanes >= K contribute e=0 / Et=0
    float na = m + LN2 * __builtin_amdgcn_logf(ss) + lgp[t * 16 + k2];
    alpha = (k2 < K) ? na : -1e30f;
  }
  float m2 = alpha;
  #pragma unroll
  for (int d = 1; d < 16; d <<= 1) m2 = fmaxf(m2, __shfl_xor(m2, d, 16));
  float e2 = __builtin_amdgcn_exp2f(LOG2E * (alpha - m2));
  #pragma unroll
  for (int d = 1; d < 16; d <<= 1) e2 += __shfl_xor(e2, d, 16);
  float logZ = m2 + LN2 * __builtin_amdgcn_logf(e2);
  float us = 0.f;
  const int* lab = labels + b * T_;
  for (int t0 = lane; t0 < L; t0 += 64){
    int la = lab[t0];
    us += lgp[t0 * 16 + la];
    if (t0 >= 1) us += tr[lab[t0 - 1] * K + la];
  }
  #pragma unroll
  for (int d = 1; d < 64; d <<= 1) us += __shfl_xor(us, d, 64);
  if (lane == 0) out[tau * B_ + b] = logZ - us;
}

extern "C" void kernel_launch(void* const* d_in, const int* in_sizes, int n_in,
                              void* d_out, int out_size, void* d_ws, size_t ws_size,
                              hipStream_t stream){
  const float* x = (const float*)d_in[0];
  const int* len = (const int*)d_in[1];
  const int* labels = (const int*)d_in[2];
  WPtrs wp;
  for (int l = 0; l < NL_; l++){
    wp.W[l] = (const float*)d_in[3 + 2 * l];
    wp.Bv[l] = (const float*)d_in[4 + 2 * l];
  }
  const float* W1 = (const float*)d_in[15];
  const float* b1 = (const float*)d_in[16];
  const float* W2 = (const float*)d_in[17];
  const float* b2 = (const float*)d_in[18];
  const float* trans1 = (const float*)d_in[19];
  const float* trans2 = (const float*)d_in[20];

  char* ws = (char*)d_ws;
  const size_t SZ_HB  = 2ull * NL_ * B_ * H_ * 2;          // 786432
  const size_t SZ_CNT = (size_t)NL_ * T_ * 4;              // 12288
  const size_t O_XB  = SZ_HB + SZ_CNT;                     // 798720
  const size_t SZ_X  = (size_t)B_ * T_ * DP_ * 2;          // 20971520
  const size_t O_XRB = O_XB + SZ_X;
  const size_t O_WHP = O_XRB + SZ_X;
  const size_t SZ_WHP = (size_t)NL_ * H_ * G4_ * 2;        // 3145728
  const size_t O_WXP = O_WHP + SZ_WHP;
  const size_t SZ_WXP = (size_t)NL_ * DP_ * G4_ * 2;       // 3932160
  const size_t O_W1T = O_WXP + SZ_WXP;
  const size_t O_W2T = O_W1T + 65536;
  const size_t O_HO  = O_W2T + 65536;
  const size_t SZ_HO = (size_t)B_ * T_ * NL_ * H_ * 2;     // 100663296
  const size_t O_LGT = O_HO + SZ_HO;

  unsigned short* hbuf = (unsigned short*)(ws + 0);
  int* cnt = (int*)(ws + SZ_HB);
  unsigned short* xb  = (unsigned short*)(ws + O_XB);
  unsigned short* xrb = (unsigned short*)(ws + O_XRB);
  unsigned short* whp = (unsigned short*)(ws + O_WHP);
  unsigned short* wxp = (unsigned short*)(ws + O_WXP);
  float* w1t = (float*)(ws + O_W1T);
  float* w2t = (float*)(ws + O_W2T);
  unsigned short* ho = (unsigned short*)(ws + O_HO);
  float* lgt = (float*)(ws + O_LGT);

  hipMemsetAsync(ws, 0, SZ_HB + SZ_CNT, stream);           // zero h_{-1} and flags
  k_prep_x<<<5120, 256, 0, stream>>>(x, len, xb, xrb);
  k_prep_w<<<1856, 256, 0, stream>>>(wp, whp, wxp, W1, W2, w1t, w2t);
  k_rec<<<128, 256, 0, stream>>>(whp, wxp, xb, xrb, wp, len, hbuf, cnt, ho);
  k_logits<<<8192, 256, 0, stream>>>(ho, w1t, w2t, b1, b2, lgt);
  k_crf<<<32, 256, 0, stream>>>(lgt, labels, len, trans1, trans2, (float*)d_out);
}